// Round 10
// baseline (228.986 us; speedup 1.0000x reference)
//
#include <hip/hip_runtime.h>
#include <hip/hip_bf16.h>
#include <hip/hip_cooperative_groups.h>
#include <math.h>

namespace cg = cooperative_groups;

#define C_N 50000

typedef float f32x16 __attribute__((ext_vector_type(16)));
typedef float f32x4v __attribute__((ext_vector_type(4)));
typedef short bf16x8 __attribute__((ext_vector_type(8)));
typedef unsigned short u16x4 __attribute__((ext_vector_type(4)));
typedef unsigned short u16x2 __attribute__((ext_vector_type(2)));
#define VZERO16 {0.f,0.f,0.f,0.f,0.f,0.f,0.f,0.f,0.f,0.f,0.f,0.f,0.f,0.f,0.f,0.f}

// ---- ws layout (float offsets, all multiples of 16) ----
#define OQP    0        // qp[4][1024] Wq partials
#define OSUMB  4096     // sumpb 512*16
#define OQKB   12288    // qkb bf16 B-fragments: 16384 ushort (8192 floats)
#define OSS    20480    // S[16]
#define OZP    20496    // zpart[4][1024]
#define OH1P   24592    // h1part[4][1024]
#define OY2P   28688    // y2part[4][1024]
#define OPA    32784    // pA[16][16384] fp32
#define OPP    294928   // pp bf16: nb*16384 ushort

__device__ __forceinline__ int brev4(int l){
  return ((l&1)<<3)|((l&2)<<1)|((l&4)>>1)|((l&8)>>3);
}

__device__ __forceinline__ float bf2f(unsigned short u){
  unsigned int x = ((unsigned int)u)<<16;
  return __builtin_bit_cast(float, x);
}

// Sum 16 values (f32x16) over 64 lanes; lanes l<16 get total for head brev4(l).
__device__ __forceinline__ float vred16(f32x16 v, int lane){
  float send, got;
#define RS(A,B,M) \
  send = (lane&M)? v[A] : v[B]; \
  got  = __shfl_xor(send, M);   \
  v[A] = ((lane&M)? v[B] : v[A]) + got;
  RS(0,8,1) RS(1,9,1) RS(2,10,1) RS(3,11,1)
  RS(4,12,1) RS(5,13,1) RS(6,14,1) RS(7,15,1)
  RS(0,4,2) RS(1,5,2) RS(2,6,2) RS(3,7,2)
  RS(0,2,4) RS(1,3,4)
  RS(0,1,8)
#undef RS
  float t = v[0];
  t += __shfl_xor(t,16);
  t += __shfl_xor(t,32);
  return t;
}

// ================= FRONT (cooperative, 256 blocks x 256 thr) =================
// PH0: Wq partials (64 jblk x 4 iseg).  sync.  PH1: Q combine + qk rows ->
// qkb in bf16 MFMA B-fragment order (kc=i>>5, rg=(i>>3)&3, jj=i&7).
__global__ __launch_bounds__(256) void hm_front(const float* __restrict__ Wq,
    const float* __restrict__ z_prev, const float* __restrict__ bq,
    const float* __restrict__ Wk, float* __restrict__ qp,
    unsigned short* __restrict__ qkb){
  __shared__ float xs[256];
  __shared__ float red[16][17];
  __shared__ float qlds[1024];
  const int tid = threadIdx.x, bid = blockIdx.x;
  // ---- PH0: mvQ partial ----
  {
    int jblk = bid>>2, iseg = bid&3;
    xs[tid] = z_prev[iseg*256 + tid];
    __syncthreads();
    int jq = tid&15, iq = tid>>4;
    const float* Wp = Wq + (size_t)(iseg*256)*1024 + jblk*16 + jq;
    float acc = 0.f;
#pragma unroll
    for (int k=0;k<16;k++){
      int il = iq + 16*k;
      acc = fmaf(xs[il], Wp[(size_t)il*1024], acc);
    }
    red[iq][jq] = acc;
    __syncthreads();
    if (tid < 16){
      float s = 0.f;
#pragma unroll
      for (int ii=0;ii<16;ii++) s += red[ii][tid];
      qp[iseg*1024 + jblk*16 + tid] = s;
    }
  }
  cg::this_grid().sync();
  // ---- PH1: Q combine + qk2 ----
  for (int k=tid;k<1024;k+=256){
    float q = bq[k];
#pragma unroll
    for (int s=0;s<4;s++) q += qp[s*1024 + k];
    qlds[k] = q;
  }
  __syncthreads();
  int w = tid>>6, l = tid&63;
  int i = bid*4 + w;
  const float* wr = Wk + (size_t)i*1024 + l;
  f32x16 acc = VZERO16;
#define QKS(k) acc[k] = wr[k*64] * qlds[k*64 + l];
  QKS(0) QKS(1) QKS(2) QKS(3) QKS(4) QKS(5) QKS(6) QKS(7)
  QKS(8) QKS(9) QKS(10) QKS(11) QKS(12) QKS(13) QKS(14) QKS(15)
#undef QKS
  float t = vred16(acc, l);
  if (l < 16){
    int h = brev4(l);
    int kc = i>>5, rg = (i>>3)&3, jj = i&7;
    __hip_bfloat16 b = __float2bfloat16(t);
    qkb[(kc*64 + rg*16 + h)*8 + jj] = *(unsigned short*)&b;
  }
}

#define LD2(AP,KC,FA,FB) \
  FA = *(const float4*)((AP)+(KC)*32); \
  FB = *(const float4*)((AP)+(KC)*32+4);
#define CVT8(FA,FB,AV) { \
  __hip_bfloat16 c0=__float2bfloat16(FA.x),c1=__float2bfloat16(FA.y); \
  __hip_bfloat16 c2=__float2bfloat16(FA.z),c3=__float2bfloat16(FA.w); \
  __hip_bfloat16 c4=__float2bfloat16(FB.x),c5=__float2bfloat16(FB.y); \
  __hip_bfloat16 c6=__float2bfloat16(FB.z),c7=__float2bfloat16(FB.w); \
  AV[0]=*(short*)&c0; AV[1]=*(short*)&c1; AV[2]=*(short*)&c2; AV[3]=*(short*)&c3; \
  AV[4]=*(short*)&c4; AV[5]=*(short*)&c5; AV[6]=*(short*)&c6; AV[7]=*(short*)&c7; }

// ============ FUSED scores(MFMA)+exp+pool (unchanged structure) =============
__global__ __launch_bounds__(256,2) void hm_fused(const float* __restrict__ nodes,
    const unsigned short* __restrict__ qkb, unsigned short* __restrict__ parts,
    float* __restrict__ sumpb){
  extern __shared__ float tile[];           // [16][1028]
  __shared__ float part[4][16][17];
  __shared__ float eb[16][16];
  const int tid = threadIdx.x, w = tid>>6, l = tid&63;
  const int rowA = l&15, kgrp = l>>4;
  const int r_ = tid>>4, h_ = tid&15;

  bf16x8 bq0,bq1,bq2,bq3,bq4,bq5,bq6,bq7;
  {
    const bf16x8* qb = (const bf16x8*)qkb;
    const int o = w*8*64 + l;
    bq0=qb[o]; bq1=qb[o+64]; bq2=qb[o+128]; bq3=qb[o+192];
    bq4=qb[o+256]; bq5=qb[o+320]; bq6=qb[o+384]; bq7=qb[o+448];
  }
  f32x16 a0 = VZERO16, a1 = VZERO16, a2 = VZERO16, a3 = VZERO16;
  float ssum = 0.f;
  const int stride = gridDim.x;

  int cb = blockIdx.x;
  float4 p0a,p0b,p1a,p1b,p2a,p2b,p3a,p3b,p4a,p4b,p5a,p5b,p6a,p6b,p7a,p7b;
  {
    const float* ap = nodes + ((size_t)(cb*16 + rowA))*1024 + w*256 + kgrp*8;
    LD2(ap,0,p0a,p0b) LD2(ap,1,p1a,p1b) LD2(ap,2,p2a,p2b) LD2(ap,3,p3a,p3b)
    LD2(ap,4,p4a,p4b) LD2(ap,5,p5a,p5b) LD2(ap,6,p6a,p6b) LD2(ap,7,p7a,p7b)
  }
  float* tw = tile + rowA*1028 + w*256 + kgrp*8;

  for (; cb < 3125; cb += stride){
    __syncthreads();                       // barrier0: prev tile fully read
    *(float4*)(tw+0*32) = p0a; *(float4*)(tw+0*32+4) = p0b;
    *(float4*)(tw+1*32) = p1a; *(float4*)(tw+1*32+4) = p1b;
    *(float4*)(tw+2*32) = p2a; *(float4*)(tw+2*32+4) = p2b;
    *(float4*)(tw+3*32) = p3a; *(float4*)(tw+3*32+4) = p3b;
    *(float4*)(tw+4*32) = p4a; *(float4*)(tw+4*32+4) = p4b;
    *(float4*)(tw+5*32) = p5a; *(float4*)(tw+5*32+4) = p5b;
    *(float4*)(tw+6*32) = p6a; *(float4*)(tw+6*32+4) = p6b;
    *(float4*)(tw+7*32) = p7a; *(float4*)(tw+7*32+4) = p7b;
    bf16x8 av0,av1,av2,av3,av4,av5,av6,av7;
    CVT8(p0a,p0b,av0) CVT8(p1a,p1b,av1) CVT8(p2a,p2b,av2) CVT8(p3a,p3b,av3)
    CVT8(p4a,p4b,av4) CVT8(p5a,p5b,av5) CVT8(p6a,p6b,av6) CVT8(p7a,p7b,av7)
    f32x4v D0 = {0.f,0.f,0.f,0.f};
    f32x4v D1 = {0.f,0.f,0.f,0.f};
    D0 = __builtin_amdgcn_mfma_f32_16x16x32_bf16(av0, bq0, D0, 0,0,0);
    D1 = __builtin_amdgcn_mfma_f32_16x16x32_bf16(av1, bq1, D1, 0,0,0);
    D0 = __builtin_amdgcn_mfma_f32_16x16x32_bf16(av2, bq2, D0, 0,0,0);
    D1 = __builtin_amdgcn_mfma_f32_16x16x32_bf16(av3, bq3, D1, 0,0,0);
    D0 = __builtin_amdgcn_mfma_f32_16x16x32_bf16(av4, bq4, D0, 0,0,0);
    D1 = __builtin_amdgcn_mfma_f32_16x16x32_bf16(av5, bq5, D1, 0,0,0);
    D0 = __builtin_amdgcn_mfma_f32_16x16x32_bf16(av6, bq6, D0, 0,0,0);
    D1 = __builtin_amdgcn_mfma_f32_16x16x32_bf16(av7, bq7, D1, 0,0,0);
    {
      int cbn = cb + stride; if (cbn >= 3125) cbn = cb;
      const float* apn = nodes + ((size_t)(cbn*16 + rowA))*1024 + w*256 + kgrp*8;
      LD2(apn,0,p0a,p0b) LD2(apn,1,p1a,p1b) LD2(apn,2,p2a,p2b) LD2(apn,3,p3a,p3b)
      LD2(apn,4,p4a,p4b) LD2(apn,5,p5a,p5b) LD2(apn,6,p6a,p6b) LD2(apn,7,p7a,p7b)
    }
#pragma unroll
    for (int i=0;i<4;i++) part[w][kgrp*4+i][rowA] = D0[i] + D1[i];
    __syncthreads();                       // barrier1
    {
      float s = part[0][r_][h_]+part[1][r_][h_]+part[2][r_][h_]+part[3][r_][h_];
      eb[r_][h_] = __expf(s * 0.125f);
    }
    __syncthreads();                       // barrier2
    if (tid < 16){
#pragma unroll
      for (int rr=0;rr<16;rr++) ssum += eb[rr][tid];
    }
    const float* tr = tile + w*256 + l*4;
#pragma unroll 4
    for (int r=0;r<16;r++){
      float4 nv = *(const float4*)(tr + r*1028);
      f32x16 u = *(const f32x16*)&eb[r][0];
      a0 += u*nv.x; a1 += u*nv.y; a2 += u*nv.z; a3 += u*nv.w;
    }
  }
  unsigned short* p = parts + (size_t)blockIdx.x*16384 + w*256 + l*4;
#pragma unroll
  for (int h=0;h<16;h++){
    __hip_bfloat16 b0=__float2bfloat16(a0[h]), b1=__float2bfloat16(a1[h]);
    __hip_bfloat16 b2=__float2bfloat16(a2[h]), b3=__float2bfloat16(a3[h]);
    u16x4 o;
    o[0]=*(unsigned short*)&b0; o[1]=*(unsigned short*)&b1;
    o[2]=*(unsigned short*)&b2; o[3]=*(unsigned short*)&b3;
    *(u16x4*)(p + h*1024) = o;
  }
  if (tid < 16) sumpb[blockIdx.x*16 + tid] = ssum;
}

// ================= TAIL (cooperative, 256 blocks x 512 thr) =================
// PH-A: partial-reduce pp(bf16)->pA[16][16384] fp32; block0 reduces S.
// PH-B: mvV partials (Pu row built on the fly from pA, L2-hot).
// PH-C: z combine (/S + bv | z_prev) -> W1 partials.
// PH-D: hb combine (b1+GELU) -> W2 partials.
// PH-E: block0: y combine + RMSNorm -> out.
__global__ __launch_bounds__(512) void hm_tail(
    const unsigned short* __restrict__ pp, const float* __restrict__ sumpb,
    float* __restrict__ pA, float* __restrict__ S,
    float* __restrict__ zpart, float* __restrict__ h1part,
    float* __restrict__ y2part,
    const float* __restrict__ Wv, const float* __restrict__ bv,
    const float* __restrict__ z_prev,
    const float* __restrict__ W1, const float* __restrict__ b1,
    const float* __restrict__ W2, const float* __restrict__ b2,
    const float* __restrict__ scale, float* __restrict__ out, int nb){
  __shared__ float xs[512];
  __shared__ float red[32][17];
  __shared__ float yb[1024];
  __shared__ float rr[8];
  __shared__ float msv;
  const int tid = threadIdx.x, bid = blockIdx.x;
  // ---- PH-A ----
  {
    int gtid = bid*512 + tid;
    int seg = gtid>>13, j2 = gtid&8191;
    int cnt = nb>>4;                        // nb multiple of 16
    float s0=0.f, s1=0.f;
    for (int b=seg*cnt; b<(seg+1)*cnt; b++){
      u16x2 v = *(const u16x2*)&pp[(size_t)b*16384 + j2*2];
      s0 += bf2f(v[0]); s1 += bf2f(v[1]);
    }
    float2 o = make_float2(s0,s1);
    *(float2*)&pA[(size_t)seg*16384 + j2*2] = o;
    if (bid == 0){
      int h = tid&15, g = tid>>4;
      float sp = 0.f;
      for (int b=g; b<nb; b+=32) sp += sumpb[b*16 + h];
      red[g][h] = sp;
      __syncthreads();
      if (tid < 16){
        float sv=0.f;
#pragma unroll
        for (int gg=0; gg<32; gg++) sv += red[gg][tid];
        S[tid] = sv;
      }
    }
  }
  cg::this_grid().sync();
  // ---- PH-B: mvV partials ----
  {
    int jblk = bid>>2, iseg = bid&3, hh = jblk>>2;
    if (tid < 256){
      float s = 0.f;
      int base = hh*1024 + iseg*256 + tid;
#pragma unroll
      for (int sg=0; sg<16; sg++) s += pA[(size_t)sg*16384 + base];
      xs[tid] = s;
    }
    __syncthreads();
    int jq = tid&15, iq = tid>>4;
    const float* Wp = Wv + (size_t)(iseg*256)*1024 + jblk*16 + jq;
    float acc = 0.f;
#pragma unroll
    for (int k=0;k<8;k++){
      int il = iq + 32*k;
      acc = fmaf(xs[il], Wp[(size_t)il*1024], acc);
    }
    red[iq][jq] = acc;
    __syncthreads();
    if (tid < 16){
      float s=0.f;
#pragma unroll
      for (int ii=0;ii<32;ii++) s += red[ii][tid];
      zpart[iseg*1024 + jblk*16 + tid] = s;
    }
  }
  cg::this_grid().sync();
  // ---- PH-C: z combine + W1 partials ----
  {
    int jblk = bid>>2, iseg = bid&3;
    int jj = iseg*512 + tid;
    float xv;
    if (jj < 1024){
      float s = 0.f;
#pragma unroll
      for (int sg=0; sg<4; sg++) s += zpart[sg*1024 + jj];
      xv = s / S[jj>>6] + bv[jj];
    } else {
      xv = z_prev[jj-1024];
    }
    xs[tid] = xv;
    __syncthreads();
    int jq = tid&15, iq = tid>>4;
    const float* Wp = W1 + (size_t)(iseg*512)*1024 + jblk*16 + jq;
    float acc = 0.f;
#pragma unroll
    for (int k=0;k<16;k++){
      int il = iq + 32*k;
      acc = fmaf(xs[il], Wp[(size_t)il*1024], acc);
    }
    red[iq][jq] = acc;
    __syncthreads();
    if (tid < 16){
      float s=0.f;
#pragma unroll
      for (int ii=0;ii<32;ii++) s += red[ii][tid];
      h1part[iseg*1024 + jblk*16 + tid] = s;
    }
  }
  cg::this_grid().sync();
  // ---- PH-D: hb combine + W2 partials ----
  {
    int jblk = bid>>2, iseg = bid&3;
    __syncthreads();                       // xs reuse fence
    if (tid < 256){
      int ii = iseg*256 + tid;
      float s = b1[ii];
#pragma unroll
      for (int sg=0; sg<4; sg++) s += h1part[sg*1024 + ii];
      xs[tid] = 0.5f * s * (1.0f + erff(s * 0.70710678118654752f));
    }
    __syncthreads();
    int jq = tid&15, iq = tid>>4;
    const float* Wp = W2 + (size_t)(iseg*256)*1024 + jblk*16 + jq;
    float acc = 0.f;
#pragma unroll
    for (int k=0;k<8;k++){
      int il = iq + 32*k;
      acc = fmaf(xs[il], Wp[(size_t)il*1024], acc);
    }
    red[iq][jq] = acc;
    __syncthreads();
    if (tid < 16){
      float s=0.f;
#pragma unroll
      for (int ii=0;ii<32;ii++) s += red[ii][tid];
      y2part[iseg*1024 + jblk*16 + tid] = s;
    }
  }
  cg::this_grid().sync();
  // ---- PH-E: y combine + RMS (block 0) ----
  if (bid == 0){
    float loc = 0.f;
    for (int j=tid; j<1024; j+=512){
      float y = b2[j];
#pragma unroll
      for (int sg=0; sg<4; sg++) y += y2part[sg*1024 + j];
      yb[j] = y;
      loc = fmaf(y,y,loc);
    }
#pragma unroll
    for (int m=1;m<64;m<<=1) loc += __shfl_xor(loc, m);
    if ((tid&63)==0) rr[tid>>6] = loc;
    __syncthreads();
    if (tid==0){
      float s = rr[0]+rr[1]+rr[2]+rr[3]+rr[4]+rr[5]+rr[6]+rr[7];
      msv = rsqrtf(s*(1.0f/1024.0f) + 1e-6f);
    }
    __syncthreads();
    float r = msv;
    for (int j=tid;j<1024;j+=512) out[j] = scale[j]*yb[j]*r;
  }
}

extern "C" void kernel_launch(void* const* d_in, const int* in_sizes, int n_in,
                              void* d_out, int out_size, void* d_ws, size_t ws_size,
                              hipStream_t stream){
  const float* nodes  = (const float*)d_in[0];
  const float* z_prev = (const float*)d_in[1];
  const float* Wq = (const float*)d_in[2];
  const float* bq = (const float*)d_in[3];
  const float* Wk = (const float*)d_in[4];
  // d_in[5] = bk — cancels in softmax, unused
  const float* Wv = (const float*)d_in[6];
  const float* bv = (const float*)d_in[7];
  const float* W1 = (const float*)d_in[8];
  const float* b1 = (const float*)d_in[9];
  const float* W2 = (const float*)d_in[10];
  const float* b2 = (const float*)d_in[11];
  const float* scale = (const float*)d_in[12];
  float* ws  = (float*)d_ws;
  float* out = (float*)d_out;

  float* qp     = ws + OQP;
  float* sumb   = ws + OSUMB;
  unsigned short* qkb = (unsigned short*)(ws + OQKB);
  float* Sv     = ws + OSS;
  float* zpart  = ws + OZP;
  float* h1part = ws + OH1P;
  float* y2part = ws + OY2P;
  float* pA     = ws + OPA;
  unsigned short* pp = (unsigned short*)(ws + OPP);

  // nb partial blocks for fused (multiple of 16, <=512)
  int nbp = 512;
  {
    size_t avail_f = ws_size/4;
    if (avail_f > (size_t)OPP){
      size_t cap = (avail_f - OPP)/8192;   // 8192 floats per partial (16384 u16)
      if ((size_t)nbp > cap) nbp = (int)cap;
    } else nbp = 16;
    nbp &= ~15;
    if (nbp < 16) nbp = 16;
  }

  const size_t tile_bytes = 16*1028*sizeof(float);  // 65792

  {
    void* fargs[] = {(void*)&Wq, (void*)&z_prev, (void*)&bq, (void*)&Wk,
                     (void*)&qp, (void*)&qkb};
    hipLaunchCooperativeKernel((const void*)hm_front, dim3(256), dim3(256),
                               fargs, 0, stream);
  }
  hm_fused<<<nbp, 256, tile_bytes, stream>>>(nodes, qkb, pp, sumb);
  {
    void* targs[] = {(void*)&pp, (void*)&sumb, (void*)&pA, (void*)&Sv,
                     (void*)&zpart, (void*)&h1part, (void*)&y2part,
                     (void*)&Wv, (void*)&bv, (void*)&z_prev,
                     (void*)&W1, (void*)&b1, (void*)&W2, (void*)&b2,
                     (void*)&scale, (void*)&out, (void*)&nbp};
    hipLaunchCooperativeKernel((const void*)hm_tail, dim3(256), dim3(512),
                               targs, 0, stream);
  }
}

// Round 11
// 87.487 us; speedup vs baseline: 2.6174x; 2.6174x over previous
//
#include <hip/hip_runtime.h>
#include <hip/hip_bf16.h>
#include <math.h>

#define C_N 50000

typedef float f32x16 __attribute__((ext_vector_type(16)));
typedef float f32x4v __attribute__((ext_vector_type(4)));
typedef short bf16x8 __attribute__((ext_vector_type(8)));
typedef unsigned short u16x4 __attribute__((ext_vector_type(4)));
#define VZERO16 {0.f,0.f,0.f,0.f,0.f,0.f,0.f,0.f,0.f,0.f,0.f,0.f,0.f,0.f,0.f,0.f}

// ---- ws layout (float offsets, all multiples of 16) ----
#define OQ     0        // Q[1024]
#define OZ     1024     // z[2048]
#define OH1P   3072     // h1part[2][1024]
#define OY     5120     // ybuf[1024]
#define OSUMB  6144     // per-block head sums 512*16
#define OQKB   14336    // qkb bf16 B-fragments: 16384 ushort (8192 floats)
#define OPP2   22528    // 2nd-level pool partials, bf16: 32*16384 ushort
#define OPP    284672   // pool partials, bf16: nb*16384 ushort

__device__ __forceinline__ int brev4(int l){
  return ((l&1)<<3)|((l&2)<<1)|((l&4)>>1)|((l&8)>>3);
}

__device__ __forceinline__ float bf2f(unsigned short u){
  unsigned int x = ((unsigned int)u)<<16;
  return __builtin_bit_cast(float, x);
}

// Sum 16 values (f32x16) over 64 lanes; lanes l<16 get total for head brev4(l).
__device__ __forceinline__ float vred16(f32x16 v, int lane){
  float send, got;
#define RS(A,B,M) \
  send = (lane&M)? v[A] : v[B]; \
  got  = __shfl_xor(send, M);   \
  v[A] = ((lane&M)? v[B] : v[A]) + got;
  RS(0,8,1) RS(1,9,1) RS(2,10,1) RS(3,11,1)
  RS(4,12,1) RS(5,13,1) RS(6,14,1) RS(7,15,1)
  RS(0,4,2) RS(1,5,2) RS(2,6,2) RS(3,7,2)
  RS(0,2,4) RS(1,3,4)
  RS(0,1,8)
#undef RS
  float t = v[0];
  t += __shfl_xor(t,16);
  t += __shfl_xor(t,32);
  return t;
}

// ---- 16-output matvec block, NT threads: out_j = sum_i x[i]*W[i*1024+j] ----
template<int IN, int NT>
__device__ __forceinline__ float mv_dot(const float* __restrict__ W,
    const float* __restrict__ x, int tid, int jblk){
  __shared__ float xs[IN];
  __shared__ float red[NT/16][17];
  for (int k=tid;k<IN;k+=NT) xs[k]=x[k];
  __syncthreads();
  int jq = tid&15, iq = tid>>4;
  int j = jblk*16 + jq;
  float acc = 0.f;
#pragma unroll 8
  for (int i=iq;i<IN;i+=NT/16)
    acc = fmaf(xs[i], W[(size_t)i*1024 + j], acc);
  red[iq][jq] = acc;
  __syncthreads();
  float s = 0.f;
  if (tid < 16){
#pragma unroll
    for (int ii=0;ii<NT/16;ii++) s += red[ii][tid];
  }
  return s;
}

// Q = z_prev@Wq + bq; also copy z_prev into z[1024:2048]
__global__ __launch_bounds__(1024) void hm_mvQ(const float* __restrict__ W,
    const float* __restrict__ x, const float* __restrict__ bq,
    float* __restrict__ Q, float* __restrict__ z){
  float s = mv_dot<1024,1024>(W, x, threadIdx.x, blockIdx.x);
  int tid = threadIdx.x;
  int j0 = blockIdx.x*16;
  if (tid < 16){
    Q[j0+tid] = s + bq[j0+tid];
    z[1024 + j0 + tid] = x[j0 + tid];
  }
}

// qk[i][h] = sum_t Wk[i][h*64+t]*Q[h*64+t]; one wave per row i.
// Writes DIRECTLY in bf16 MFMA B-fragment order:
// flat bf16 idx = (kc*64 + rg*16 + h)*8 + jj with kc=i>>5, rg=(i>>3)&3, jj=i&7.
__global__ __launch_bounds__(256) void hm_qk2(const float* __restrict__ Wk,
    const float* __restrict__ Q, unsigned short* __restrict__ qkb){
  __shared__ float qlds[1024];
  int tid = threadIdx.x;
  for (int k=tid;k<1024;k+=256) qlds[k]=Q[k];
  __syncthreads();
  int w = tid>>6, l = tid&63;
  int i = blockIdx.x*4 + w;
  const float* wr = Wk + (size_t)i*1024 + l;
  f32x16 acc = VZERO16;
#define QKS(k) acc[k] = wr[k*64] * qlds[k*64 + l];
  QKS(0) QKS(1) QKS(2) QKS(3) QKS(4) QKS(5) QKS(6) QKS(7)
  QKS(8) QKS(9) QKS(10) QKS(11) QKS(12) QKS(13) QKS(14) QKS(15)
#undef QKS
  float t = vred16(acc, l);
  if (l < 16){
    int h = brev4(l);
    int kc = i>>5, rg = (i>>3)&3, jj = i&7;
    __hip_bfloat16 b = __float2bfloat16(t);
    qkb[(kc*64 + rg*16 + h)*8 + jj] = *(unsigned short*)&b;
  }
}

#define LD2(AP,KC,FA,FB) \
  FA = *(const float4*)((AP)+(KC)*32); \
  FB = *(const float4*)((AP)+(KC)*32+4);
#define CVT8(FA,FB,AV) { \
  __hip_bfloat16 c0=__float2bfloat16(FA.x),c1=__float2bfloat16(FA.y); \
  __hip_bfloat16 c2=__float2bfloat16(FA.z),c3=__float2bfloat16(FA.w); \
  __hip_bfloat16 c4=__float2bfloat16(FB.x),c5=__float2bfloat16(FB.y); \
  __hip_bfloat16 c6=__float2bfloat16(FB.z),c7=__float2bfloat16(FB.w); \
  AV[0]=*(short*)&c0; AV[1]=*(short*)&c1; AV[2]=*(short*)&c2; AV[3]=*(short*)&c3; \
  AV[4]=*(short*)&c4; AV[5]=*(short*)&c5; AV[6]=*(short*)&c6; AV[7]=*(short*)&c7; }

// Fused scores(MFMA)+exp+pool with LDS tile staging (single nodes read).
// 2 barriers/cb. barrier0 REMOVED (proof): the tile is wave-private by
// column band — wave w writes only cols [w*256,w*256+256) (tw offsets
// kgrp*8+kc*32+{0..7} < 256) and pool reads only cols w*256+l*4+{0..3} —
// so write(i+1) vs pool-read(i) ordering is per-wave program order.
// part[] writes are [w]-indexed (wave-private), reads fenced by barrier1;
// eb write(i+1) vs read(i) fenced by barrier1(i+1) (all waves must finish
// pool(i) to reach it). launch_bounds(256,2): ~215 VGPR live; the 128-cap
// version spilled accs (243MB scratch, 183us) — keep 256 cap.
__global__ __launch_bounds__(256,2) void hm_fused(const float* __restrict__ nodes,
    const unsigned short* __restrict__ qkb, unsigned short* __restrict__ parts,
    float* __restrict__ sumpb){
  extern __shared__ float tile[];           // [16][1028]
  __shared__ float part[4][16][17];
  __shared__ float eb[16][16];
  const int tid = threadIdx.x, w = tid>>6, l = tid&63;
  const int rowA = l&15, kgrp = l>>4;
  const int r_ = tid>>4, h_ = tid&15;

  bf16x8 bq0,bq1,bq2,bq3,bq4,bq5,bq6,bq7;
  {
    const bf16x8* qb = (const bf16x8*)qkb;
    const int o = w*8*64 + l;
    bq0=qb[o]; bq1=qb[o+64]; bq2=qb[o+128]; bq3=qb[o+192];
    bq4=qb[o+256]; bq5=qb[o+320]; bq6=qb[o+384]; bq7=qb[o+448];
  }
  f32x16 a0 = VZERO16, a1 = VZERO16, a2 = VZERO16, a3 = VZERO16;
  float ssum = 0.f;
  const int stride = gridDim.x;

  int cb = blockIdx.x;
  float4 p0a,p0b,p1a,p1b,p2a,p2b,p3a,p3b,p4a,p4b,p5a,p5b,p6a,p6b,p7a,p7b;
  {
    const float* ap = nodes + ((size_t)(cb*16 + rowA))*1024 + w*256 + kgrp*8;
    LD2(ap,0,p0a,p0b) LD2(ap,1,p1a,p1b) LD2(ap,2,p2a,p2b) LD2(ap,3,p3a,p3b)
    LD2(ap,4,p4a,p4b) LD2(ap,5,p5a,p5b) LD2(ap,6,p6a,p6b) LD2(ap,7,p7a,p7b)
  }
  float* tw = tile + rowA*1028 + w*256 + kgrp*8;

  for (; cb < 3125; cb += stride){
    // park this cb's fp32 fragments in LDS (wave-private columns, no barrier)
    *(float4*)(tw+0*32) = p0a; *(float4*)(tw+0*32+4) = p0b;
    *(float4*)(tw+1*32) = p1a; *(float4*)(tw+1*32+4) = p1b;
    *(float4*)(tw+2*32) = p2a; *(float4*)(tw+2*32+4) = p2b;
    *(float4*)(tw+3*32) = p3a; *(float4*)(tw+3*32+4) = p3b;
    *(float4*)(tw+4*32) = p4a; *(float4*)(tw+4*32+4) = p4b;
    *(float4*)(tw+5*32) = p5a; *(float4*)(tw+5*32+4) = p5b;
    *(float4*)(tw+6*32) = p6a; *(float4*)(tw+6*32+4) = p6b;
    *(float4*)(tw+7*32) = p7a; *(float4*)(tw+7*32+4) = p7b;
    bf16x8 av0,av1,av2,av3,av4,av5,av6,av7;
    CVT8(p0a,p0b,av0) CVT8(p1a,p1b,av1) CVT8(p2a,p2b,av2) CVT8(p3a,p3b,av3)
    CVT8(p4a,p4b,av4) CVT8(p5a,p5b,av5) CVT8(p6a,p6b,av6) CVT8(p7a,p7b,av7)
    f32x4v D0 = {0.f,0.f,0.f,0.f};
    f32x4v D1 = {0.f,0.f,0.f,0.f};
    D0 = __builtin_amdgcn_mfma_f32_16x16x32_bf16(av0, bq0, D0, 0,0,0);
    D1 = __builtin_amdgcn_mfma_f32_16x16x32_bf16(av1, bq1, D1, 0,0,0);
    D0 = __builtin_amdgcn_mfma_f32_16x16x32_bf16(av2, bq2, D0, 0,0,0);
    D1 = __builtin_amdgcn_mfma_f32_16x16x32_bf16(av3, bq3, D1, 0,0,0);
    D0 = __builtin_amdgcn_mfma_f32_16x16x32_bf16(av4, bq4, D0, 0,0,0);
    D1 = __builtin_amdgcn_mfma_f32_16x16x32_bf16(av5, bq5, D1, 0,0,0);
    D0 = __builtin_amdgcn_mfma_f32_16x16x32_bf16(av6, bq6, D0, 0,0,0);
    D1 = __builtin_amdgcn_mfma_f32_16x16x32_bf16(av7, bq7, D1, 0,0,0);
    {
      int cbn = cb + stride; if (cbn >= 3125) cbn = cb;
      const float* apn = nodes + ((size_t)(cbn*16 + rowA))*1024 + w*256 + kgrp*8;
      LD2(apn,0,p0a,p0b) LD2(apn,1,p1a,p1b) LD2(apn,2,p2a,p2b) LD2(apn,3,p3a,p3b)
      LD2(apn,4,p4a,p4b) LD2(apn,5,p5a,p5b) LD2(apn,6,p6a,p6b) LD2(apn,7,p7a,p7b)
    }
#pragma unroll
    for (int i=0;i<4;i++) part[w][kgrp*4+i][rowA] = D0[i] + D1[i];
    __syncthreads();                       // barrier1: part ready
    {
      float s = part[0][r_][h_]+part[1][r_][h_]+part[2][r_][h_]+part[3][r_][h_];
      eb[r_][h_] = __expf(s * 0.125f);
    }
    __syncthreads();                       // barrier2: eb ready
    if (tid < 16){
#pragma unroll
      for (int rr=0;rr<16;rr++) ssum += eb[rr][tid];
    }
    const float* tr = tile + w*256 + l*4;
#pragma unroll 4
    for (int r=0;r<16;r++){
      float4 nv = *(const float4*)(tr + r*1028);
      f32x16 u = *(const f32x16*)&eb[r][0];
      a0 += u*nv.x; a1 += u*nv.y; a2 += u*nv.z; a3 += u*nv.w;
    }
  }
  unsigned short* p = parts + (size_t)blockIdx.x*16384 + w*256 + l*4;
#pragma unroll
  for (int h=0;h<16;h++){
    __hip_bfloat16 b0=__float2bfloat16(a0[h]), b1=__float2bfloat16(a1[h]);
    __hip_bfloat16 b2=__float2bfloat16(a2[h]), b3=__float2bfloat16(a3[h]);
    u16x4 o;
    o[0]=*(unsigned short*)&b0; o[1]=*(unsigned short*)&b1;
    o[2]=*(unsigned short*)&b2; o[3]=*(unsigned short*)&b3;
    *(u16x4*)(p + h*1024) = o;
  }
  if (tid < 16) sumpb[blockIdx.x*16 + tid] = ssum;
}

// Stage A: pp2[y][j] = sum of 16 bf16 partials; u16x4 per thread (8B loads)
__global__ __launch_bounds__(256) void hm_predA(const unsigned short* __restrict__ parts,
    unsigned short* __restrict__ pp2, int nb){
  int j4 = blockIdx.x*256 + threadIdx.x;   // 0..4095, each covers 4 j's
  int b0 = blockIdx.y*16;
  int b1 = b0+16 < nb ? b0+16 : nb;
  float s0=0.f, s1=0.f, s2=0.f, s3=0.f;
  for (int b=b0;b<b1;b++){
    u16x4 v = *(const u16x4*)&parts[(size_t)b*16384 + j4*4];
    s0 += bf2f(v[0]); s1 += bf2f(v[1]); s2 += bf2f(v[2]); s3 += bf2f(v[3]);
  }
  __hip_bfloat16 r0=__float2bfloat16(s0), r1=__float2bfloat16(s1);
  __hip_bfloat16 r2=__float2bfloat16(s2), r3=__float2bfloat16(s3);
  u16x4 o;
  o[0]=*(unsigned short*)&r0; o[1]=*(unsigned short*)&r1;
  o[2]=*(unsigned short*)&r2; o[3]=*(unsigned short*)&r3;
  *(u16x4*)&pp2[(size_t)blockIdx.y*16384 + j4*4] = o;
}

// z[j] = (Pu[h]·Wv[:,j])/S[h] + bv[j]; Pu row hh summed from bf16 pp2
// in-kernel; S[h] reduced inline from sumpb. 1024 threads.
__global__ __launch_bounds__(1024) void hm_mvV(const float* __restrict__ W,
    const unsigned short* __restrict__ pp2, const float* __restrict__ sumpb,
    const float* __restrict__ bv, float* __restrict__ z, int ny, int nb){
  __shared__ float xs[1024];
  __shared__ float red[64][17];
  __shared__ float ssl[16];
  const int tid = threadIdx.x;
  const int hh = blockIdx.x>>2;
  float sacc = 0.f;
  for (int b=tid; b<nb; b+=1024) sacc += sumpb[b*16 + hh];
#pragma unroll
  for (int m=1;m<64;m<<=1) sacc += __shfl_xor(sacc, m);
  if ((tid&63)==0) ssl[tid>>6] = sacc;
  {
    int k = tid;
    float s = 0.f;
    for (int y=0;y<ny;y++) s += bf2f(pp2[(size_t)y*16384 + hh*1024 + k]);
    xs[k] = s;
  }
  __syncthreads();
  int jq = tid&15, iq = tid>>4;
  int j = blockIdx.x*16 + jq;
  float acc = 0.f;
#pragma unroll 8
  for (int i=iq;i<1024;i+=64)
    acc = fmaf(xs[i], W[(size_t)i*1024 + j], acc);
  red[iq][jq] = acc;
  __syncthreads();
  if (tid < 16){
    float s = 0.f;
#pragma unroll
    for (int ii=0;ii<64;ii++) s += red[ii][tid];
    float S = 0.f;
#pragma unroll
    for (int q=0;q<16;q++) S += ssl[q];
    int jo = blockIdx.x*16 + tid;
    z[jo] = s / S + bv[jo];
  }
}

// W1 partials, grid (64,2): iseg halves of the 2048-row W1. No b1/GELU here
// (folded into mvW2 staging).
__global__ __launch_bounds__(1024) void hm_mvW1(const float* __restrict__ W,
    const float* __restrict__ z, float* __restrict__ h1part){
  __shared__ float xs[1024];
  __shared__ float red[64][17];
  const int tid = threadIdx.x;
  const int iseg = blockIdx.y;
  xs[tid] = z[iseg*1024 + tid];
  __syncthreads();
  int jq = tid&15, iq = tid>>4;
  int j = blockIdx.x*16 + jq;
  const float* Wp = W + (size_t)(iseg*1024)*1024;
  float acc = 0.f;
#pragma unroll
  for (int k=0;k<16;k++){
    int i = iq + 64*k;
    acc = fmaf(xs[i], Wp[(size_t)i*1024 + j], acc);
  }
  red[iq][jq] = acc;
  __syncthreads();
  if (tid < 16){
    float s = 0.f;
#pragma unroll
    for (int ii=0;ii<64;ii++) s += red[ii][tid];
    h1part[iseg*1024 + blockIdx.x*16 + tid] = s;
  }
}

// mvW2: stage hb = GELU(h1part[0]+h1part[1]+b1), then 1024-dot + b2.
__global__ __launch_bounds__(1024) void hm_mvW2(const float* __restrict__ W,
    const float* __restrict__ h1part, const float* __restrict__ b1,
    const float* __restrict__ b2, float* __restrict__ y){
  __shared__ float xs[1024];
  __shared__ float red[64][17];
  const int tid = threadIdx.x;
  {
    float s = b1[tid] + h1part[tid] + h1part[1024 + tid];
    xs[tid] = 0.5f * s * (1.0f + erff(s * 0.70710678118654752f));
  }
  __syncthreads();
  int jq = tid&15, iq = tid>>4;
  int j = blockIdx.x*16 + jq;
  float acc = 0.f;
#pragma unroll
  for (int k=0;k<16;k++){
    int i = iq + 64*k;
    acc = fmaf(xs[i], W[(size_t)i*1024 + j], acc);
  }
  red[iq][jq] = acc;
  __syncthreads();
  if (tid < 16){
    float s = 0.f;
#pragma unroll
    for (int ii=0;ii<64;ii++) s += red[ii][tid];
    int jo = blockIdx.x*16 + tid;
    y[jo] = s + b2[jo];
  }
}

__global__ __launch_bounds__(256) void hm_rms(const float* __restrict__ y,
    const float* __restrict__ scale, float* __restrict__ out){
  __shared__ float red[4];
  __shared__ float msv;
  int tid = threadIdx.x;
  float local = 0.f;
  for (int j=tid;j<1024;j+=256){ float t = y[j]; local = fmaf(t,t,local); }
#pragma unroll
  for (int m=1;m<64;m<<=1) local += __shfl_xor(local, m);
  if ((tid&63)==0) red[tid>>6] = local;
  __syncthreads();
  if (tid==0){
    float s = red[0]+red[1]+red[2]+red[3];
    msv = rsqrtf(s*(1.0f/1024.0f) + 1e-6f);
  }
  __syncthreads();
  float r = msv;
  for (int j=tid;j<1024;j+=256) out[j] = scale[j]*y[j]*r;
}

extern "C" void kernel_launch(void* const* d_in, const int* in_sizes, int n_in,
                              void* d_out, int out_size, void* d_ws, size_t ws_size,
                              hipStream_t stream){
  const float* nodes  = (const float*)d_in[0];
  const float* z_prev = (const float*)d_in[1];
  const float* Wq = (const float*)d_in[2];
  const float* bq = (const float*)d_in[3];
  const float* Wk = (const float*)d_in[4];
  // d_in[5] = bk — cancels in softmax, unused
  const float* Wv = (const float*)d_in[6];
  const float* bv = (const float*)d_in[7];
  const float* W1 = (const float*)d_in[8];
  const float* b1 = (const float*)d_in[9];
  const float* W2 = (const float*)d_in[10];
  const float* b2 = (const float*)d_in[11];
  const float* scale = (const float*)d_in[12];
  float* ws  = (float*)d_ws;
  float* out = (float*)d_out;

  float* Qv     = ws + OQ;
  float* z      = ws + OZ;
  float* h1part = ws + OH1P;
  float* ybuf   = ws + OY;
  float* sumb   = ws + OSUMB;
  unsigned short* qkb = (unsigned short*)(ws + OQKB);
  unsigned short* pp2 = (unsigned short*)(ws + OPP2);
  unsigned short* pp  = (unsigned short*)(ws + OPP);

  size_t need0 = (size_t)OPP*4;
  int nbp = 1;
  if (ws_size > need0 + 32768) nbp = (int)((ws_size - need0)/32768);
  if (nbp > 512) nbp = 512;
  if (nbp < 1) nbp = 1;
  int ny = (nbp + 15)/16;   // <= 32

  const size_t tile_bytes = 16*1028*sizeof(float);  // 65792

  hm_mvQ   <<<64,  1024, 0, stream>>>(Wq, z_prev, bq, Qv, z);
  hm_qk2   <<<256, 256, 0, stream>>>(Wk, Qv, qkb);
  hm_fused <<<nbp, 256, tile_bytes, stream>>>(nodes, qkb, pp, sumb);
  hm_predA <<<dim3(16,ny), 256, 0, stream>>>(pp, pp2, nbp);
  hm_mvV   <<<64,  1024, 0, stream>>>(Wv, pp2, sumb, bv, z, ny, nbp);
  hm_mvW1  <<<dim3(64,2), 1024, 0, stream>>>(W1, z, h1part);
  hm_mvW2  <<<64,  1024, 0, stream>>>(W2, h1part, b1, b2, ybuf);
  hm_rms   <<<1,   256, 0, stream>>>(ybuf, scale, out);
}